// Round 7
// baseline (271.328 us; speedup 1.0000x reference)
//
#include <hip/hip_runtime.h>
#include <math.h>

#define NB 8
#define NN 4096
#define NDIM 512
#define NH 8
#define NDH 64
#define QKVC 1536
#define NROWS (NB * NN)
#define EPSF 1e-5f
#define INV_N (1.0f / 4096.0f)
// log2(10000)/16
#define L2_10K_16 0.8304820237218406f

typedef __bf16 bf16x8_t __attribute__((ext_vector_type(8)));
typedef float f32x4_t __attribute__((ext_vector_type(4)));
typedef unsigned short u16x8 __attribute__((ext_vector_type(8)));

__device__ inline unsigned short f2bf(float f) {
    unsigned u = __builtin_bit_cast(unsigned, f);
    u += 0x7fff + ((u >> 16) & 1);          // round-to-nearest-even
    return (unsigned short)(u >> 16);
}
__device__ inline float bf2f(unsigned short u) {
    unsigned v = (unsigned)u << 16;
    return __builtin_bit_cast(float, v);
}

// async global->LDS, 16B per lane; LDS dest = wave-uniform base + lane*16
#define GLOAD_LDS16(g, s) __builtin_amdgcn_global_load_lds(                    \
    (const __attribute__((address_space(1))) void*)(g),                        \
    (__attribute__((address_space(3))) void*)(s), 16, 0, 0)

#define VMCNT4 asm volatile("s_waitcnt vmcnt(4)" ::: "memory")
#define VMCNT3 asm volatile("s_waitcnt vmcnt(3)" ::: "memory")
#define VMCNT0 asm volatile("s_waitcnt vmcnt(0)" ::: "memory")
#define BARF   { __builtin_amdgcn_s_barrier(); asm volatile("" ::: "memory"); }

// ---------------------------------------------------------------------------
// One kernel: fp32->bf16 for x / Wqkv / Wout, plus zeroing dots.
// ---------------------------------------------------------------------------
__device__ inline void cvt8v(const float* __restrict__ s,
                             unsigned short* __restrict__ d, int i)
{
    float4 a = *(const float4*)(s + i);
    float4 b = *(const float4*)(s + i + 4);
    ushort4 lo, hi;
    lo.x = f2bf(a.x); lo.y = f2bf(a.y); lo.z = f2bf(a.z); lo.w = f2bf(a.w);
    hi.x = f2bf(b.x); hi.y = f2bf(b.y); hi.z = f2bf(b.z); hi.w = f2bf(b.w);
    *(ushort4*)(d + i)     = lo;
    *(ushort4*)(d + i + 4) = hi;
}

__global__ __launch_bounds__(256)
void cvt_all(const float* __restrict__ x,  const float* __restrict__ wq,
             const float* __restrict__ wo,
             unsigned short* __restrict__ xb, unsigned short* __restrict__ wqb,
             unsigned short* __restrict__ wob, float* __restrict__ dots)
{
    const int bid = blockIdx.x, t = threadIdx.x;
    if (bid < 8192) {                       // x: 16.78M elems
        cvt8v(x, xb, (bid * 256 + t) * 8);
    } else if (bid < 8576) {                // Wqkv: 786432 elems
        cvt8v(wq, wqb, ((bid - 8192) * 256 + t) * 8);
    } else if (bid < 8704) {                // Wout: 262144 elems
        cvt8v(wo, wob, ((bid - 8576) * 256 + t) * 8);
    } else {                                // zero dots: 262144 floats
        const float4 z = {0.f, 0.f, 0.f, 0.f};
        float4* dp = (float4*)dots + (size_t)((bid - 8704) * 256 + t) * 4;
        dp[0] = z; dp[1] = z; dp[2] = z; dp[3] = z;
    }
}

// ---------------------------------------------------------------------------
// Shared GEMM core (256x128 tile, BK=32, 8 waves 4Mx2N): 3-deep circular LDS
// (72 KB, 2 blocks/CU), ONE barrier per K-step, 2-step load slack.
//   step t: vmcnt(3) [tile-t loads, issued at step t-2, complete];
//           barrier  [all waves' t-loads visible; t-1 reads retired];
//           stage(t+2) [safe: overwrites buf read at step t-1, retired];
//           ds_read(t) + 16 MFMA.
// Swizzle: LDS[r][c16] = G[r][c16 ^ ((r>>1)&3)], applied on global source
// (rule 21) and on frag reads (2-way bank aliasing = free).
// ---------------------------------------------------------------------------
#define GEMM_CORE(Asrc_, Bsrc_)                                                \
    f32x4_t acc[4][4] = {};                                                    \
    const int fr = lane & 15;                                                  \
    const int fq = lane >> 4;                                                  \
    const int ch0 = ((fq ^ ((fr >> 1) & 3)) << 3);                             \
    const int rl = tid >> 2;                                                   \
    const int cs = (((tid & 3) ^ ((rl >> 1) & 3)) << 3);                       \
    const unsigned short* Asrc = (Asrc_) + (size_t)rl * NDIM + cs;             \
    const unsigned short* Bsrc = (Bsrc_) + (size_t)rl * NDIM + cs;             \
    const int sdst = wave * 512;                                               \
    STG_A(0, 0); STG_A(0, 1); STG_B(0);                                        \
    STG_A(1, 0); STG_A(1, 1); STG_B(1);                                        \
    _Pragma("unroll")                                                          \
    for (int tt = 0; tt < 16; ++tt) {                                          \
        if (tt == 15) VMCNT0; else VMCNT3;                                     \
        BARF;                                                                  \
        if (tt < 14) { STG_A(tt + 2, 0); STG_A(tt + 2, 1); STG_B(tt + 2); }    \
        bf16x8_t af[4], bfr[4];                                                \
        const int ab = (tt % 3) * 12288;                                       \
        const int bb = ab + 8192;                                              \
        _Pragma("unroll")                                                      \
        for (int mi = 0; mi < 4; ++mi)                                         \
            af[mi] = *(const bf16x8_t*)&lds[ab + (warp_m * 64 + mi * 16 + fr) * 32 + ch0]; \
        _Pragma("unroll")                                                      \
        for (int nj = 0; nj < 4; ++nj)                                         \
            bfr[nj] = *(const bf16x8_t*)&lds[bb + (warp_n * 64 + nj * 16 + fr) * 32 + ch0]; \
        __builtin_amdgcn_s_setprio(1);                                         \
        _Pragma("unroll")                                                      \
        for (int mi = 0; mi < 4; ++mi)                                         \
            _Pragma("unroll")                                                  \
            for (int nj = 0; nj < 4; ++nj)                                     \
                acc[mi][nj] = __builtin_amdgcn_mfma_f32_16x16x32_bf16(         \
                    af[mi], bfr[nj], acc[mi][nj], 0, 0, 0);                    \
        __builtin_amdgcn_s_setprio(0);                                         \
    }

#define STG_A(tt, c) GLOAD_LDS16(Asrc + (size_t)((c) * 128) * NDIM + (tt) * 32, \
        &lds[((tt) % 3) * 12288 + ((c) * 4096) + sdst])
#define STG_B(tt)    GLOAD_LDS16(Bsrc + (tt) * 32, \
        &lds[((tt) % 3) * 12288 + 8192 + sdst])

// ---------------------------------------------------------------------------
// K/V GEMM: cols 512..1535 of qkv. Epilogue: LN + RoPE(k), transposed stores.
// ---------------------------------------------------------------------------
__global__ __launch_bounds__(512, 4)
void gemm_kv_fused(const unsigned short* __restrict__ A,
                   const unsigned short* __restrict__ Bm,
                   const float* __restrict__ pos,
                   const float* __restrict__ gk, const float* __restrict__ bk,
                   const float* __restrict__ gv, const float* __restrict__ bvv,
                   unsigned short* __restrict__ kT,
                   unsigned short* __restrict__ vT)
{
    __shared__ __align__(16) unsigned short lds[36864];   // 72 KB

    const int tid  = threadIdx.x;
    const int wave = tid >> 6;
    const int lane = tid & 63;

    // bijective XCD swizzle (nwg = 1024)
    int flat = blockIdx.y * 8 + blockIdx.x;
    flat = (flat & 7) * 128 + (flat >> 3);
    const int bx = flat & 7;
    const int by = flat >> 3;
    const int m0 = by * 256;
    const int n0 = bx * 128;            // 0..1023 within k|v span

    const int warp_m = wave >> 1;       // 0..3 -> rows warp_m*64
    const int warp_n = wave & 1;        // 0..1 -> cols warp_n*64 (one head)

    GEMM_CORE(A + (size_t)m0 * NDIM, Bm + (size_t)n0 * NDIM)

    // ---- epilogue: LN always; RoPE iff k; transposed store ----
    const int nc = n0 + warp_n * 64;            // 0..1023 (k: <512, v: >=512)
    const int isK = (nc < 512);
    const int c  = lane & 15;
    const int g4 = (lane >> 4) * 4;
    const int mrow0 = m0 + warp_m * 64;
    const int h = (nc >> 6) & 7;

    {                                   // LN over head dim
        const float* gamma = isK ? gk : gv;
        const float* beta  = isK ? bk : bvv;
        float gm[4], bt[4];
        #pragma unroll
        for (int j = 0; j < 4; ++j) { gm[j] = gamma[j * 16 + c]; bt[j] = beta[j * 16 + c]; }
        #pragma unroll
        for (int i = 0; i < 4; ++i)
            #pragma unroll
            for (int r = 0; r < 4; ++r) {
                float t0 = acc[i][0][r], t1 = acc[i][1][r];
                float t2 = acc[i][2][r], t3 = acc[i][3][r];
                float s  = t0 + t1 + t2 + t3;
                float ss = t0*t0 + t1*t1 + t2*t2 + t3*t3;
                #pragma unroll
                for (int msk = 1; msk < 16; msk <<= 1) {
                    s  += __shfl_xor(s,  msk, 64);
                    ss += __shfl_xor(ss, msk, 64);
                }
                const float mu = s * (1.0f / 64.0f);
                const float rs = rsqrtf(ss * (1.0f / 64.0f) - mu * mu + EPSF);
                acc[i][0][r] = (t0 - mu) * rs * gm[0] + bt[0];
                acc[i][1][r] = (t1 - mu) * rs * gm[1] + bt[1];
                acc[i][2][r] = (t2 - mu) * rs * gm[2] + bt[2];
                acc[i][3][r] = (t3 - mu) * rs * gm[3] + bt[3];
            }
    }
    if (isK) {                          // RoPE 2D (k only)
        const float Kc = 64.0f * exp2f(-(float)c * L2_10K_16);
        #pragma unroll
        for (int i = 0; i < 4; ++i)
            #pragma unroll
            for (int r = 0; r < 4; ++r) {
                const int row = mrow0 + i * 16 + g4 + r;
                const float2 p = ((const float2*)pos)[row];
                float sx, cx, sy, cy;
                __sincosf(p.x * Kc, &sx, &cx);
                __sincosf(p.y * Kc, &sy, &cy);
                const float t0 = acc[i][0][r], t1 = acc[i][1][r];
                const float t2 = acc[i][2][r], t3 = acc[i][3][r];
                acc[i][0][r] = t0 * cx - t1 * sx;
                acc[i][1][r] = t1 * cx + t0 * sx;
                acc[i][2][r] = t2 * cy - t3 * sy;
                acc[i][3][r] = t3 * cy + t2 * sy;
            }
    }
    unsigned short* T = isK ? kT : vT;
    #pragma unroll
    for (int i = 0; i < 4; ++i) {
        const int row = mrow0 + i * 16 + g4;
        const int bb2 = row >> 12;          // batch
        const int nl = row & 4095;          // n within batch (4-aligned)
        #pragma unroll
        for (int j = 0; j < 4; ++j) {
            ushort4 o;
            o.x = f2bf(acc[i][j][0]); o.y = f2bf(acc[i][j][1]);
            o.z = f2bf(acc[i][j][2]); o.w = f2bf(acc[i][j][3]);
            *(ushort4*)(T + ((size_t)((bb2 * NH + h) * 64 + j * 16 + c)) * NN + nl) = o;
        }
    }
}

// ---------------------------------------------------------------------------
// Q GEMM: cols 0..511 of qkv. Epilogue: RoPE, row-major qb.
// ---------------------------------------------------------------------------
__global__ __launch_bounds__(512, 4)
void gemm_q_fused(const unsigned short* __restrict__ A,
                  const unsigned short* __restrict__ Bm,
                  const float* __restrict__ pos,
                  unsigned short* __restrict__ qb)
{
    __shared__ __align__(16) unsigned short lds[36864];

    const int tid  = threadIdx.x;
    const int wave = tid >> 6;
    const int lane = tid & 63;

    // bijective XCD swizzle (nwg = 512)
    int flat = blockIdx.y * 4 + blockIdx.x;
    flat = (flat & 7) * 64 + (flat >> 3);
    const int bx = flat & 3;
    const int by = flat >> 2;
    const int m0 = by * 256;
    const int n0 = bx * 128;

    const int warp_m = wave >> 1;
    const int warp_n = wave & 1;

    GEMM_CORE(A + (size_t)m0 * NDIM, Bm + (size_t)n0 * NDIM)

    const int nc = n0 + warp_n * 64;
    const int c  = lane & 15;
    const int g4 = (lane >> 4) * 4;
    const int mrow0 = m0 + warp_m * 64;

    {                                   // RoPE 2D
        const float Kc = 64.0f * exp2f(-(float)c * L2_10K_16);
        #pragma unroll
        for (int i = 0; i < 4; ++i)
            #pragma unroll
            for (int r = 0; r < 4; ++r) {
                const int row = mrow0 + i * 16 + g4 + r;
                const float2 p = ((const float2*)pos)[row];
                float sx, cx, sy, cy;
                __sincosf(p.x * Kc, &sx, &cx);
                __sincosf(p.y * Kc, &sy, &cy);
                const float t0 = acc[i][0][r], t1 = acc[i][1][r];
                const float t2 = acc[i][2][r], t3 = acc[i][3][r];
                acc[i][0][r] = t0 * cx - t1 * sx;
                acc[i][1][r] = t1 * cx + t0 * sx;
                acc[i][2][r] = t2 * cy - t3 * sy;
                acc[i][3][r] = t3 * cy + t2 * sy;
            }
    }
    #pragma unroll
    for (int i = 0; i < 4; ++i)
        #pragma unroll
        for (int j = 0; j < 4; ++j) {
            unsigned short* qp = qb + (size_t)(mrow0 + i * 16 + g4) * NDIM
                               + nc + j * 16 + c;
            #pragma unroll
            for (int r = 0; r < 4; ++r)
                qp[(size_t)r * NDIM] = f2bf(acc[i][j][r]);
        }
}

// ---------------------------------------------------------------------------
// out[m][d'] = sum_hd q[m,hd] * M2b[b][d'][hd] + bout[d']   (fp32 out)
// ---------------------------------------------------------------------------
__global__ __launch_bounds__(512, 4)
void gemm_out_mfma(const unsigned short* __restrict__ qb,
                   const unsigned short* __restrict__ M2b,
                   const float* __restrict__ bias, float* __restrict__ C)
{
    __shared__ __align__(16) unsigned short lds[36864];

    const int tid  = threadIdx.x;
    const int wave = tid >> 6;
    const int lane = tid & 63;

    // bijective XCD swizzle (nwg = 512)
    int flat = blockIdx.y * 4 + blockIdx.x;
    flat = (flat & 7) * 64 + (flat >> 3);
    const int bx = flat & 3;
    const int by = flat >> 2;
    const int m0 = by * 256;                 // global row (incl. batch)
    const int n0 = bx * 128;
    const int b  = m0 >> 12;                 // batch

    const int warp_m = wave >> 1;
    const int warp_n = wave & 1;

    GEMM_CORE(qb + (size_t)m0 * NDIM,
              M2b + (size_t)b * NDIM * NDIM + (size_t)n0 * NDIM)

    const int c  = lane & 15;
    const int g4 = (lane >> 4) * 4;
    const int mrow0 = m0 + warp_m * 64;
    const int ncol = n0 + warp_n * 64;

    #pragma unroll
    for (int j = 0; j < 4; ++j) {
        const int col = ncol + j * 16 + c;
        const float bb2 = bias[col];
        #pragma unroll
        for (int i = 0; i < 4; ++i) {
            float* cp = C + (size_t)(mrow0 + i * 16 + g4) * NDIM + col;
            #pragma unroll
            for (int r = 0; r < 4; ++r)
                cp[(size_t)r * NDIM] = acc[i][j][r] + bb2;
        }
    }
}

// ---------------------------------------------------------------------------
// dots[b][h][d][e] = sum_n kT[b,h,d,n] * vT[b,h,e,n]  -- MFMA NT-GEMM.
// 3-buffer (48 KB -> 3 blocks/CU), one barrier/step, 2-step load slack.
// ---------------------------------------------------------------------------
__global__ __launch_bounds__(256)
void dots_mfma(const unsigned short* __restrict__ kT,
               const unsigned short* __restrict__ vT,
               float* __restrict__ dots)
{
    __shared__ __align__(16) unsigned short sk[3][64 * 64];
    __shared__ __align__(16) unsigned short sv[3][64 * 64];
    const int t = threadIdx.x;
    const int w = t >> 6, l = t & 63;
    const int bh = blockIdx.z * NH + blockIdx.y;
    const int n0 = blockIdx.x * 512;

    const int r8 = l >> 3;                     // 0..7
    const int cs = ((l & 7) ^ r8) * 8;         // swizzled source chunk (shorts)
    const unsigned short* ksrc = kT + (size_t)(bh * 64 + w * 16 + r8) * NN + n0 + cs;
    const unsigned short* vsrc = vT + (size_t)(bh * 64 + w * 16 + r8) * NN + n0 + cs;

#define STGK(ss, q) GLOAD_LDS16(ksrc + (size_t)(q) * 8 * NN + (ss) * 64, \
        &sk[(ss) % 3][w * 1024 + (q) * 512])
#define STGV(ss, q) GLOAD_LDS16(vsrc + (size_t)(q) * 8 * NN + (ss) * 64, \
        &sv[(ss) % 3][w * 1024 + (q) * 512])

    const int fr = l & 15, fq = l >> 4;
    const int doff = (w >> 1) * 32, eoff = (w & 1) * 32;

    f32x4_t acc[2][2] = {};

    STGK(0, 0); STGK(0, 1); STGV(0, 0); STGV(0, 1);
    STGK(1, 0); STGK(1, 1); STGV(1, 0); STGV(1, 1);

    #pragma unroll
    for (int s = 0; s < 8; ++s) {
        if (s == 7) VMCNT0; else VMCNT4;
        __builtin_amdgcn_s_barrier();
        asm volatile("" ::: "memory");
        if (s < 6) { STGK(s + 2, 0); STGK(s + 2, 1); STGV(s + 2, 0); STGV(s + 2, 1); }
        const int buf = s % 3;
        bf16x8_t ak[2][2], bv[2][2];
        #pragma unroll
        for (int di = 0; di < 2; ++di)
            #pragma unroll
            for (int ks = 0; ks < 2; ++ks)
                ak[di][ks] = *(const bf16x8_t*)
                    &sk[buf][(doff + di * 16 + fr) * 64 + (((ks * 4 + fq) ^ (fr & 7)) * 8)];
        #pragma unroll
        for (int ej = 0; ej < 2; ++ej)
            #pragma unroll
            for (int ks = 0; ks < 2; ++ks)
                bv[ej][ks] = *(const bf16x8_t*)
                    &sv[buf][(eoff + ej * 16 + fr) * 64 + (((ks * 4 + fq) ^ (fr & 7)) * 8)];
        __builtin_amdgcn_s_setprio(1);
        #pragma unroll
        for (int ks = 0; ks < 2; ++ks)
            #pragma unroll
            for (int di = 0; di < 2; ++di)
                #pragma unroll
                for (int ej = 0; ej < 2; ++ej)
                    acc[di][ej] = __builtin_amdgcn_mfma_f32_16x16x32_bf16(
                        ak[di][ks], bv[ej][ks], acc[di][ej], 0, 0, 0);
        __builtin_amdgcn_s_setprio(0);
    }
#undef STGK
#undef STGV

    float* dp = dots + (size_t)bh * 64 * 64;
    const int cc = l & 15;
    const int rr = (l >> 4) * 4;
    #pragma unroll
    for (int di = 0; di < 2; ++di)
        #pragma unroll
        for (int ej = 0; ej < 2; ++ej)
            #pragma unroll
            for (int r = 0; r < 4; ++r)
                atomicAdd(dp + (doff + di * 16 + rr + r) * 64 + eoff + ej * 16 + cc,
                          acc[di][ej][r]);
}

// ---------------------------------------------------------------------------
// M2b[b][d'][h*64+d] = bf16( sum_e (dots[b,h,d,e]/N) * Woutb[d', h*64+e] )
// ---------------------------------------------------------------------------
__global__ __launch_bounds__(256)
void dotsw_mfma(const unsigned short* __restrict__ Woutb,
                const float* __restrict__ dots,
                unsigned short* __restrict__ M2b)
{
    __shared__ unsigned short As[128 * 64];   // Wout tile, row-major (16 KB)
    __shared__ unsigned short Bs[64 * 64];    // dots[b,h] bf16, row-major (8 KB)
    const int t = threadIdx.x;
    const int wave = t >> 6;
    const int lane = t & 63;
    const int dp0 = blockIdx.x * 128;
    const int h = blockIdx.y, b = blockIdx.z;

    const int srow = lane >> 3;               // 0..7
    const int scol = (lane & 7) * 8;
    const unsigned short* Ag = Woutb + (size_t)(dp0 + wave * 32 + srow) * NDIM
                             + h * NDH + scol;
    #pragma unroll
    for (int i = 0; i < 4; ++i)
        GLOAD_LDS16(Ag + (size_t)i * 8 * NDIM, As + wave * 2048 + i * 512);

    // B tile: read fp32 dots, scale by 1/N, convert to bf16 into Bs
    {
        const float* Dg = dots + (size_t)(b * NH + h) * 4096;
        const int dr = t >> 2;                // 0..63
        const int dc = (t & 3) * 16;          // 0,16,32,48
        const float* dgp = Dg + dr * 64 + dc;
        float4 f0 = *(const float4*)(dgp);
        float4 f1 = *(const float4*)(dgp + 4);
        float4 f2 = *(const float4*)(dgp + 8);
        float4 f3 = *(const float4*)(dgp + 12);
        ushort4 o0, o1, o2, o3;
        o0.x = f2bf(f0.x * INV_N); o0.y = f2bf(f0.y * INV_N);
        o0.z = f2bf(f0.z * INV_N); o0.w = f2bf(f0.w * INV_N);
        o1.x = f2bf(f1.x * INV_N); o1.y = f2bf(f1.y * INV_N);
        o1.z = f2bf(f1.z * INV_N); o1.w = f2bf(f1.w * INV_N);
        o2.x = f2bf(f2.x * INV_N); o2.y = f2bf(f2.y * INV_N);
        o2.z = f2bf(f2.z * INV_N); o2.w = f2bf(f2.w * INV_N);
        o3.x = f2bf(f3.x * INV_N); o3.y = f2bf(f3.y * INV_N);
        o3.z = f2bf(f3.z * INV_N); o3.w = f2bf(f3.w * INV_N);
        *(ushort4*)&Bs[dr * 64 + dc]      = o0;
        *(ushort4*)&Bs[dr * 64 + dc + 4]  = o1;
        *(ushort4*)&Bs[dr * 64 + dc + 8]  = o2;
        *(ushort4*)&Bs[dr * 64 + dc + 12] = o3;
    }
    __syncthreads();

    const int wm = (wave >> 1) * 64;          // d' quadrant
    const int wn = (wave & 1) * 32;           // d half
    const int fr = lane & 15;
    const int fq = (lane >> 4) * 8;

    f32x4_t acc[4][2] = {};
    #pragma unroll
    for (int kk = 0; kk < 2; ++kk) {
        bf16x8_t af[4], bf[2];
        #pragma unroll
        for (int i = 0; i < 4; ++i)
            af[i] = *(const bf16x8_t*)&As[(wm + i * 16 + fr) * 64 + kk * 32 + fq];
        #pragma unroll
        for (int j = 0; j < 2; ++j)
            bf[j] = *(const bf16x8_t*)&Bs[(wn + j * 16 + fr) * 64 + kk * 32 + fq];
        #pragma unroll
        for (int i = 0; i < 4; ++i)
            #pragma unroll
            for (int j = 0; j < 2; ++j)
                acc[i][j] = __builtin_amdgcn_mfma_f32_16x16x32_bf16(
                    af[i], bf[j], acc[i][j], 0, 0, 0);
    }

    const int c  = lane & 15;
    const int g4 = (lane >> 4) * 4;
    #pragma unroll
    for (int i = 0; i < 4; ++i)
        #pragma unroll
        for (int j = 0; j < 2; ++j) {
            unsigned short* mp = M2b + ((size_t)(b * NDIM) + dp0 + wm + i * 16 + g4) * NDIM
                               + h * NDH + wn + j * 16 + c;
            #pragma unroll
            for (int r = 0; r < 4; ++r)
                mp[(size_t)r * NDIM] = f2bf(acc[i][j][r]);
        }
}

// ---------------------------------------------------------------------------
extern "C" void kernel_launch(void* const* d_in, const int* in_sizes, int n_in,
                              void* d_out, int out_size, void* d_ws, size_t ws_size,
                              hipStream_t stream)
{
    const float* x    = (const float*)d_in[0];
    const float* pos  = (const float*)d_in[1];
    const float* Wqkv = (const float*)d_in[2];
    const float* gk   = (const float*)d_in[3];
    const float* bk   = (const float*)d_in[4];
    const float* gv   = (const float*)d_in[5];
    const float* bv   = (const float*)d_in[6];
    const float* Wout = (const float*)d_in[7];
    const float* bout = (const float*)d_in[8];
    float* out = (float*)d_out;

    // ws: dots f32(1M) | M2b(4M) | qb(32M) | kT(32M) | vT(32M) | xb(32M)
    //     | Wqkvb(1.5M) | Woutb(.5M)
    float* dots = (float*)d_ws;
    unsigned short* M2b     = (unsigned short*)(dots + (size_t)NB * NH * 64 * 64);
    unsigned short* qb      = M2b + (size_t)NB * NDIM * NDIM;
    unsigned short* kT      = qb + (size_t)NROWS * NDIM;
    unsigned short* vT      = kT + (size_t)NB * NH * NDH * NN;
    unsigned short* xb      = vT + (size_t)NB * NH * NDH * NN;
    unsigned short* Wqkvb   = xb + (size_t)NROWS * NDIM;
    unsigned short* Woutb   = Wqkvb + (size_t)QKVC * NDIM;

    // 1) all fp32->bf16 converts + dots zeroing, one launch
    cvt_all<<<dim3(8768), dim3(256), 0, stream>>>(x, Wqkv, Wout, xb, Wqkvb, Woutb, dots);
    // 2a) k/v -> kT/vT (transposed), LN + RoPE(k) fused
    gemm_kv_fused<<<dim3(8, NROWS / 256), dim3(512), 0, stream>>>(
        xb, Wqkvb + (size_t)512 * NDIM, pos, gk, bk, gv, bv, kT, vT);
    // 2b) q -> qb row-major, RoPE fused
    gemm_q_fused<<<dim3(4, NROWS / 256), dim3(512), 0, stream>>>(
        xb, Wqkvb, pos, qb);
    // 3) dots = k^T v per (b,h)  -- MFMA, fp32 atomics
    dots_mfma<<<dim3(NN / 512, NH, NB), dim3(256), 0, stream>>>(kT, vT, dots);
    // 4) M2b[b] = ((dots[b]/N) @ blockdiag) x Wout^T  (cvt fused in)
    dotsw_mfma<<<dim3(NDIM / 128, NH, NB), dim3(256), 0, stream>>>(Woutb, dots, M2b);
    // 5) out = q @ M2b[b]^T + bout  (3-deep, 1 barrier/step, fp32 out)
    gemm_out_mfma<<<dim3(NDIM / 128, NROWS / 256), dim3(512), 0, stream>>>(
        qb, M2b, bout, out);
}

// Round 8
// 268.046 us; speedup vs baseline: 1.0122x; 1.0122x over previous
//
#include <hip/hip_runtime.h>
#include <math.h>

#define NB 8
#define NN 4096
#define NDIM 512
#define NH 8
#define NDH 64
#define QKVC 1536
#define NROWS (NB * NN)
#define EPSF 1e-5f
#define INV_N (1.0f / 4096.0f)
// log2(10000)/16
#define L2_10K_16 0.8304820237218406f

typedef __bf16 bf16x8_t __attribute__((ext_vector_type(8)));
typedef float f32x4_t __attribute__((ext_vector_type(4)));
typedef unsigned short u16x8 __attribute__((ext_vector_type(8)));

__device__ inline unsigned short f2bf(float f) {
    unsigned u = __builtin_bit_cast(unsigned, f);
    u += 0x7fff + ((u >> 16) & 1);          // round-to-nearest-even
    return (unsigned short)(u >> 16);
}
__device__ inline float bf2f(unsigned short u) {
    unsigned v = (unsigned)u << 16;
    return __builtin_bit_cast(float, v);
}

// async global->LDS, 16B per lane; LDS dest = wave-uniform base + lane*16
#define GLOAD_LDS16(g, s) __builtin_amdgcn_global_load_lds(                    \
    (const __attribute__((address_space(1))) void*)(g),                        \
    (__attribute__((address_space(3))) void*)(s), 16, 0, 0)

// ---------------------------------------------------------------------------
// One kernel: fp32->bf16 for x / Wqkv / Wout, plus zeroing dots.
// ---------------------------------------------------------------------------
__device__ inline void cvt8v(const float* __restrict__ s,
                             unsigned short* __restrict__ d, int i)
{
    float4 a = *(const float4*)(s + i);
    float4 b = *(const float4*)(s + i + 4);
    ushort4 lo, hi;
    lo.x = f2bf(a.x); lo.y = f2bf(a.y); lo.z = f2bf(a.z); lo.w = f2bf(a.w);
    hi.x = f2bf(b.x); hi.y = f2bf(b.y); hi.z = f2bf(b.z); hi.w = f2bf(b.w);
    *(ushort4*)(d + i)     = lo;
    *(ushort4*)(d + i + 4) = hi;
}

__global__ __launch_bounds__(256)
void cvt_all(const float* __restrict__ x,  const float* __restrict__ wq,
             const float* __restrict__ wo,
             unsigned short* __restrict__ xb, unsigned short* __restrict__ wqb,
             unsigned short* __restrict__ wob, float* __restrict__ dots)
{
    const int bid = blockIdx.x, t = threadIdx.x;
    if (bid < 8192) {                       // x: 16.78M elems
        cvt8v(x, xb, (bid * 256 + t) * 8);
    } else if (bid < 8576) {                // Wqkv: 786432 elems
        cvt8v(wq, wqb, ((bid - 8192) * 256 + t) * 8);
    } else if (bid < 8704) {                // Wout: 262144 elems
        cvt8v(wo, wob, ((bid - 8576) * 256 + t) * 8);
    } else {                                // zero dots: 262144 floats
        const float4 z = {0.f, 0.f, 0.f, 0.f};
        float4* dp = (float4*)dots + (size_t)((bid - 8704) * 256 + t) * 4;
        dp[0] = z; dp[1] = z; dp[2] = z; dp[3] = z;
    }
}

// ---------------------------------------------------------------------------
// Shared GEMM core -- the measured-best (R1) structure: 256x128 tile, BK=64,
// 8 waves (4M x 2N, per-wave C 64x64 = one head), 3-deep circular LDS
// (3 x 48 KB = 144 KB, 1 block/CU), counted vmcnt(6), 2 phases per K-tile,
// 16 MFMA per phase. 599 TF measured (R1/R2) vs 516 for the BK=32 variants.
// Swizzle: LDS[r][c16] = G[r][c16 ^ (r&7)], applied on global source
// (rule 21) and on frag reads.
// Race-freedom: group t reads buf[t%3], stages tile t+2 into buf[(t+2)%3] ==
// buf[(t-1)%3] whose reads retired a barrier ago; vmcnt(6) at group end =
// exactly tile t+1 landed (6 loads/tile in flight).
// ---------------------------------------------------------------------------
#define STG_A(tt, a) GLOAD_LDS16(Asrc + (size_t)(a) * 64 * NDIM + (tt) * 64,   \
        &lds[((tt) % 3) * 24576 + (a) * 4096 + wave * 512])
#define STG_B(tt, bb) GLOAD_LDS16(Bsrc + (size_t)(bb) * 64 * NDIM + (tt) * 64, \
        &lds[((tt) % 3) * 24576 + 16384 + (bb) * 4096 + wave * 512])

#define GEMM_CORE64(Abase_, Bbase_)                                            \
    f32x4_t acc[4][4] = {};                                                    \
    const int fr = lane & 15;                                                  \
    const int fq = lane >> 4;                                                  \
    const int rc = fr & 7;                                                     \
    const int wm = warp_m * 64;                                                \
    const int wn = warp_n * 64;                                                \
    const int row8 = lane >> 3;                                                \
    const int csrc = ((lane & 7) ^ row8) * 8;                                  \
    const unsigned short* Asrc = (Abase_) + (size_t)(wave * 8 + row8) * NDIM + csrc; \
    const unsigned short* Bsrc = (Bbase_) + (size_t)(wave * 8 + row8) * NDIM + csrc; \
    STG_A(0, 0); STG_A(0, 1); STG_A(0, 2); STG_A(0, 3);                        \
    STG_B(0, 0); STG_B(0, 1);                                                  \
    STG_A(1, 0); STG_A(1, 1); STG_A(1, 2); STG_A(1, 3);                        \
    STG_B(1, 0); STG_B(1, 1);                                                  \
    asm volatile("s_waitcnt vmcnt(6)" ::: "memory");                           \
    __builtin_amdgcn_s_barrier();                                              \
    _Pragma("unroll")                                                          \
    for (int tt = 0; tt < 8; ++tt) {                                           \
        const unsigned short* Ab = &lds[(tt % 3) * 24576];                     \
        const unsigned short* Bb = Ab + 16384;                                 \
        _Pragma("unroll")                                                      \
        for (int kh = 0; kh < 2; ++kh) {                                       \
            const int ch = (((kh << 2) | fq) ^ rc) * 8;                        \
            bf16x8_t af[4], bfrag[4];                                          \
            _Pragma("unroll")                                                  \
            for (int mi = 0; mi < 4; ++mi)                                     \
                af[mi] = *(const bf16x8_t*)&Ab[(wm + mi * 16 + fr) * 64 + ch]; \
            _Pragma("unroll")                                                  \
            for (int nj = 0; nj < 4; ++nj)                                     \
                bfrag[nj] = *(const bf16x8_t*)&Bb[(wn + nj * 16 + fr) * 64 + ch]; \
            if (tt < 6) {                                                      \
                if (kh == 0) { STG_A(tt + 2, 0); STG_A(tt + 2, 1); STG_A(tt + 2, 2); } \
                else         { STG_A(tt + 2, 3); STG_B(tt + 2, 0); STG_B(tt + 2, 1); } \
            }                                                                  \
            __builtin_amdgcn_s_barrier();                                      \
            __builtin_amdgcn_s_setprio(1);                                     \
            _Pragma("unroll")                                                  \
            for (int mi = 0; mi < 4; ++mi)                                     \
                _Pragma("unroll")                                              \
                for (int nj = 0; nj < 4; ++nj)                                 \
                    acc[mi][nj] = __builtin_amdgcn_mfma_f32_16x16x32_bf16(     \
                        af[mi], bfrag[nj], acc[mi][nj], 0, 0, 0);              \
            __builtin_amdgcn_s_setprio(0);                                     \
            if (kh == 1) {                                                     \
                if (tt < 6)       asm volatile("s_waitcnt vmcnt(6)" ::: "memory"); \
                else if (tt == 6) asm volatile("s_waitcnt vmcnt(0)" ::: "memory"); \
            }                                                                  \
            __builtin_amdgcn_s_barrier();                                      \
        }                                                                      \
    }

// ---------------------------------------------------------------------------
// K/V GEMM: cols 512..1535 of qkv (Bm pre-offset). Epilogue: LN + RoPE(k),
// transposed stores kT/vT [b,h,d,n].
// ---------------------------------------------------------------------------
__global__ __launch_bounds__(512, 2)
void gemm_kv_fused(const unsigned short* __restrict__ A,
                   const unsigned short* __restrict__ Bm,
                   const float* __restrict__ pos,
                   const float* __restrict__ gk, const float* __restrict__ bk,
                   const float* __restrict__ gv, const float* __restrict__ bvv,
                   unsigned short* __restrict__ kT,
                   unsigned short* __restrict__ vT)
{
    __shared__ __align__(16) unsigned short lds[3 * 24576];   // 144 KB

    const int tid  = threadIdx.x; (void)tid;
    const int wave = threadIdx.x >> 6;
    const int lane = threadIdx.x & 63;

    // bijective XCD swizzle (nwg = 1024)
    int flat = blockIdx.y * 8 + blockIdx.x;
    flat = (flat & 7) * 128 + (flat >> 3);
    const int bx = flat & 7;
    const int by = flat >> 3;
    const int m0 = by * 256;
    const int n0 = bx * 128;            // 0..1023 within k|v span

    const int warp_m = wave >> 1;       // 0..3 -> rows warp_m*64
    const int warp_n = wave & 1;        // 0..1 -> cols warp_n*64 (one head)

    GEMM_CORE64(A + (size_t)m0 * NDIM, Bm + (size_t)n0 * NDIM)

    // ---- epilogue: LN always; RoPE iff k; transposed store ----
    const int nc = n0 + warp_n * 64;            // 0..1023 (k: <512, v: >=512)
    const int isK = (nc < 512);
    const int c  = lane & 15;
    const int g4 = (lane >> 4) * 4;
    const int mrow0 = m0 + warp_m * 64;
    const int h = (nc >> 6) & 7;

    {                                   // LN over head dim
        const float* gamma = isK ? gk : gv;
        const float* beta  = isK ? bk : bvv;
        float gm[4], bt[4];
        #pragma unroll
        for (int j = 0; j < 4; ++j) { gm[j] = gamma[j * 16 + c]; bt[j] = beta[j * 16 + c]; }
        #pragma unroll
        for (int i = 0; i < 4; ++i)
            #pragma unroll
            for (int r = 0; r < 4; ++r) {
                float t0 = acc[i][0][r], t1 = acc[i][1][r];
                float t2 = acc[i][2][r], t3 = acc[i][3][r];
                float s  = t0 + t1 + t2 + t3;
                float ss = t0*t0 + t1*t1 + t2*t2 + t3*t3;
                #pragma unroll
                for (int msk = 1; msk < 16; msk <<= 1) {
                    s  += __shfl_xor(s,  msk, 64);
                    ss += __shfl_xor(ss, msk, 64);
                }
                const float mu = s * (1.0f / 64.0f);
                const float rs = rsqrtf(ss * (1.0f / 64.0f) - mu * mu + EPSF);
                acc[i][0][r] = (t0 - mu) * rs * gm[0] + bt[0];
                acc[i][1][r] = (t1 - mu) * rs * gm[1] + bt[1];
                acc[i][2][r] = (t2 - mu) * rs * gm[2] + bt[2];
                acc[i][3][r] = (t3 - mu) * rs * gm[3] + bt[3];
            }
    }
    if (isK) {                          // RoPE 2D (k only)
        const float Kc = 64.0f * exp2f(-(float)c * L2_10K_16);
        #pragma unroll
        for (int i = 0; i < 4; ++i)
            #pragma unroll
            for (int r = 0; r < 4; ++r) {
                const int row = mrow0 + i * 16 + g4 + r;
                const float2 p = ((const float2*)pos)[row];
                float sx, cx, sy, cy;
                __sincosf(p.x * Kc, &sx, &cx);
                __sincosf(p.y * Kc, &sy, &cy);
                const float t0 = acc[i][0][r], t1 = acc[i][1][r];
                const float t2 = acc[i][2][r], t3 = acc[i][3][r];
                acc[i][0][r] = t0 * cx - t1 * sx;
                acc[i][1][r] = t1 * cx + t0 * sx;
                acc[i][2][r] = t2 * cy - t3 * sy;
                acc[i][3][r] = t3 * cy + t2 * sy;
            }
    }
    unsigned short* T = isK ? kT : vT;
    #pragma unroll
    for (int i = 0; i < 4; ++i) {
        const int row = mrow0 + i * 16 + g4;
        const int bb2 = row >> 12;          // batch
        const int nl = row & 4095;          // n within batch (4-aligned)
        #pragma unroll
        for (int j = 0; j < 4; ++j) {
            ushort4 o;
            o.x = f2bf(acc[i][j][0]); o.y = f2bf(acc[i][j][1]);
            o.z = f2bf(acc[i][j][2]); o.w = f2bf(acc[i][j][3]);
            *(ushort4*)(T + ((size_t)((bb2 * NH + h) * 64 + j * 16 + c)) * NN + nl) = o;
        }
    }
}

// ---------------------------------------------------------------------------
// Q GEMM: cols 0..511 of qkv. Epilogue: RoPE, row-major qb.
// ---------------------------------------------------------------------------
__global__ __launch_bounds__(512, 2)
void gemm_q_fused(const unsigned short* __restrict__ A,
                  const unsigned short* __restrict__ Bm,
                  const float* __restrict__ pos,
                  unsigned short* __restrict__ qb)
{
    __shared__ __align__(16) unsigned short lds[3 * 24576];

    const int tid  = threadIdx.x; (void)tid;
    const int wave = threadIdx.x >> 6;
    const int lane = threadIdx.x & 63;

    // bijective XCD swizzle (nwg = 512)
    int flat = blockIdx.y * 4 + blockIdx.x;
    flat = (flat & 7) * 64 + (flat >> 3);
    const int bx = flat & 3;
    const int by = flat >> 2;
    const int m0 = by * 256;
    const int n0 = bx * 128;

    const int warp_m = wave >> 1;
    const int warp_n = wave & 1;

    GEMM_CORE64(A + (size_t)m0 * NDIM, Bm + (size_t)n0 * NDIM)

    const int nc = n0 + warp_n * 64;
    const int c  = lane & 15;
    const int g4 = (lane >> 4) * 4;
    const int mrow0 = m0 + warp_m * 64;

    {                                   // RoPE 2D
        const float Kc = 64.0f * exp2f(-(float)c * L2_10K_16);
        #pragma unroll
        for (int i = 0; i < 4; ++i)
            #pragma unroll
            for (int r = 0; r < 4; ++r) {
                const int row = mrow0 + i * 16 + g4 + r;
                const float2 p = ((const float2*)pos)[row];
                float sx, cx, sy, cy;
                __sincosf(p.x * Kc, &sx, &cx);
                __sincosf(p.y * Kc, &sy, &cy);
                const float t0 = acc[i][0][r], t1 = acc[i][1][r];
                const float t2 = acc[i][2][r], t3 = acc[i][3][r];
                acc[i][0][r] = t0 * cx - t1 * sx;
                acc[i][1][r] = t1 * cx + t0 * sx;
                acc[i][2][r] = t2 * cy - t3 * sy;
                acc[i][3][r] = t3 * cy + t2 * sy;
            }
    }
    #pragma unroll
    for (int i = 0; i < 4; ++i)
        #pragma unroll
        for (int j = 0; j < 4; ++j) {
            unsigned short* qp = qb + (size_t)(mrow0 + i * 16 + g4) * NDIM
                               + nc + j * 16 + c;
            #pragma unroll
            for (int r = 0; r < 4; ++r)
                qp[(size_t)r * NDIM] = f2bf(acc[i][j][r]);
        }
}

// ---------------------------------------------------------------------------
// out[m][d'] = sum_hd q[m,hd] * M2b[b][d'][hd] + bout[d']   (fp32 out)
// ---------------------------------------------------------------------------
__global__ __launch_bounds__(512, 2)
void gemm_out_mfma(const unsigned short* __restrict__ qb,
                   const unsigned short* __restrict__ M2b,
                   const float* __restrict__ bias, float* __restrict__ C)
{
    __shared__ __align__(16) unsigned short lds[3 * 24576];

    const int tid  = threadIdx.x; (void)tid;
    const int wave = threadIdx.x >> 6;
    const int lane = threadIdx.x & 63;

    // bijective XCD swizzle (nwg = 512)
    int flat = blockIdx.y * 4 + blockIdx.x;
    flat = (flat & 7) * 64 + (flat >> 3);
    const int bx = flat & 3;
    const int by = flat >> 2;
    const int m0 = by * 256;                 // global row (incl. batch)
    const int n0 = bx * 128;
    const int b  = m0 >> 12;                 // batch

    const int warp_m = wave >> 1;
    const int warp_n = wave & 1;

    GEMM_CORE64(qb + (size_t)m0 * NDIM,
                M2b + (size_t)b * NDIM * NDIM + (size_t)n0 * NDIM)

    const int c  = lane & 15;
    const int g4 = (lane >> 4) * 4;
    const int mrow0 = m0 + warp_m * 64;
    const int ncol = n0 + warp_n * 64;

    #pragma unroll
    for (int j = 0; j < 4; ++j) {
        const int col = ncol + j * 16 + c;
        const float bb2 = bias[col];
        #pragma unroll
        for (int i = 0; i < 4; ++i) {
            float* cp = C + (size_t)(mrow0 + i * 16 + g4) * NDIM + col;
            #pragma unroll
            for (int r = 0; r < 4; ++r)
                cp[(size_t)r * NDIM] = acc[i][j][r] + bb2;
        }
    }
}

// ---------------------------------------------------------------------------
// dots[b][h][d][e] = sum_n kT[b,h,d,n] * vT[b,h,e,n]  -- MFMA NT-GEMM.
// (R6 version: 2-buf, 32 KB, 4 waves, fp32 atomics out.)
// ---------------------------------------------------------------------------
__global__ __launch_bounds__(256)
void dots_mfma(const unsigned short* __restrict__ kT,
               const unsigned short* __restrict__ vT,
               float* __restrict__ dots)
{
    __shared__ __align__(16) unsigned short sk[2][64 * 64];
    __shared__ __align__(16) unsigned short sv[2][64 * 64];
    const int t = threadIdx.x;
    const int w = t >> 6, l = t & 63;
    const int bh = blockIdx.z * NH + blockIdx.y;
    const int n0 = blockIdx.x * 512;

    const int r8 = l >> 3;                     // 0..7
    const int cs = ((l & 7) ^ r8) * 8;         // swizzled source chunk (shorts)
    const unsigned short* ksrc = kT + (size_t)(bh * 64 + w * 16 + r8) * NN + n0 + cs;
    const unsigned short* vsrc = vT + (size_t)(bh * 64 + w * 16 + r8) * NN + n0 + cs;

#define STGK(buf, kt, q) GLOAD_LDS16(ksrc + (size_t)(q) * 8 * NN + (kt), \
        &sk[buf][w * 1024 + (q) * 512])
#define STGV(buf, kt, q) GLOAD_LDS16(vsrc + (size_t)(q) * 8 * NN + (kt), \
        &sv[buf][w * 1024 + (q) * 512])

    const int fr = l & 15, fq = l >> 4;
    const int doff = (w >> 1) * 32, eoff = (w & 1) * 32;

    f32x4_t acc[2][2] = {};

    STGK(0, 0, 0); STGK(0, 0, 1); STGV(0, 0, 0); STGV(0, 0, 1);

    for (int s = 0; s < 8; ++s) {
        const int buf = s & 1;
        asm volatile("s_waitcnt vmcnt(0)" ::: "memory");
        __builtin_amdgcn_s_barrier();
        bf16x8_t ak[2][2], bv[2][2];
        #pragma unroll
        for (int di = 0; di < 2; ++di)
            #pragma unroll
            for (int ks = 0; ks < 2; ++ks)
                ak[di][ks] = *(const bf16x8_t*)
                    &sk[buf][(doff + di * 16 + fr) * 64 + (((ks * 4 + fq) ^ (fr & 7)) * 8)];
        #pragma unroll
        for (int ej = 0; ej < 2; ++ej)
            #pragma unroll
            for (int ks = 0; ks < 2; ++ks)
                bv[ej][ks] = *(const bf16x8_t*)
                    &sv[buf][(eoff + ej * 16 + fr) * 64 + (((ks * 4 + fq) ^ (fr & 7)) * 8)];
        if (s + 1 < 8) {
            const int nb = buf ^ 1, kt = (s + 1) * 64;
            STGK(nb, kt, 0); STGK(nb, kt, 1); STGV(nb, kt, 0); STGV(nb, kt, 1);
        }
        #pragma unroll
        for (int ks = 0; ks < 2; ++ks)
            #pragma unroll
            for (int di = 0; di < 2; ++di)
                #pragma unroll
                for (int ej = 0; ej < 2; ++ej)
                    acc[di][ej] = __builtin_amdgcn_mfma_f32_16x16x32_bf16(
                        ak[di][ks], bv[ej][ks], acc[di][ej], 0, 0, 0);
    }
#undef STGK
#undef STGV

    float* dp = dots + (size_t)bh * 64 * 64;
    const int cc = l & 15;
    const int rr = (l >> 4) * 4;
    #pragma unroll
    for (int di = 0; di < 2; ++di)
        #pragma unroll
        for (int ej = 0; ej < 2; ++ej)
            #pragma unroll
            for (int r = 0; r < 4; ++r)
                atomicAdd(dp + (doff + di * 16 + rr + r) * 64 + eoff + ej * 16 + cc,
                          acc[di][ej][r]);
}

// ---------------------------------------------------------------------------
// M2b[b][d'][h*64+d] = bf16( sum_e (dots[b,h,d,e]/N) * Woutb[d', h*64+e] )
// ---------------------------------------------------------------------------
__global__ __launch_bounds__(256)
void dotsw_mfma(const unsigned short* __restrict__ Woutb,
                const float* __restrict__ dots,
                unsigned short* __restrict__ M2b)
{
    __shared__ unsigned short As[128 * 64];   // Wout tile, row-major (16 KB)
    __shared__ unsigned short Bs[64 * 64];    // dots[b,h] bf16, row-major (8 KB)
    const int t = threadIdx.x;
    const int wave = t >> 6;
    const int lane = t & 63;
    const int dp0 = blockIdx.x * 128;
    const int h = blockIdx.y, b = blockIdx.z;

    const int srow = lane >> 3;               // 0..7
    const int scol = (lane & 7) * 8;
    const unsigned short* Ag = Woutb + (size_t)(dp0 + wave * 32 + srow) * NDIM
                             + h * NDH + scol;
    #pragma unroll
    for (int i = 0; i < 4; ++i)
        GLOAD_LDS16(Ag + (size_t)i * 8 * NDIM, As + wave * 2048 + i * 512);

    // B tile: read fp32 dots, scale by 1/N, convert to bf16 into Bs
    {
        const float* Dg = dots + (size_t)(b * NH + h) * 4096;
        const int dr = t >> 2;                // 0..63
        const int dc = (t & 3) * 16;          // 0,16,32,48
        const float* dgp = Dg + dr * 64 + dc;
        float4 f0 = *(const float4*)(dgp);
        float4 f1 = *(const float4*)(dgp + 4);
        float4 f2 = *(const float4*)(dgp + 8);
        float4 f3 = *(const float4*)(dgp + 12);
        ushort4 o0, o1, o2, o3;
        o0.x = f2bf(f0.x * INV_N); o0.y = f2bf(f0.y * INV_N);
        o0.z = f2bf(f0.z * INV_N); o0.w = f2bf(f0.w * INV_N);
        o1.x = f2bf(f1.x * INV_N); o1.y = f2bf(f1.y * INV_N);
        o1.z = f2bf(f1.z * INV_N); o1.w = f2bf(f1.w * INV_N);
        o2.x = f2bf(f2.x * INV_N); o2.y = f2bf(f2.y * INV_N);
        o2.z = f2bf(f2.z * INV_N); o2.w = f2bf(f2.w * INV_N);
        o3.x = f2bf(f3.x * INV_N); o3.y = f2bf(f3.y * INV_N);
        o3.z = f2bf(f3.z * INV_N); o3.w = f2bf(f3.w * INV_N);
        *(ushort4*)&Bs[dr * 64 + dc]      = o0;
        *(ushort4*)&Bs[dr * 64 + dc + 4]  = o1;
        *(ushort4*)&Bs[dr * 64 + dc + 8]  = o2;
        *(ushort4*)&Bs[dr * 64 + dc + 12] = o3;
    }
    __syncthreads();

    const int wm = (wave >> 1) * 64;          // d' quadrant
    const int wn = (wave & 1) * 32;           // d half
    const int fr = lane & 15;
    const int fq = (lane >> 4) * 8;

    f32x4_t acc[4][2] = {};
    #pragma unroll
    for (int kk = 0; kk < 2; ++kk) {
        bf16x8_t af[4], bf[2];
        #pragma unroll
        for (int i = 0; i < 4; ++i)
            af[i] = *(const bf16x8_t*)&As[(wm + i * 16 + fr) * 64 + kk * 32 + fq];
        #pragma unroll
        for (int j = 0; j < 2; ++j)
            bf[j] = *(const bf16x8_t*)&Bs[(wn + j * 16 + fr) * 64 + kk * 32 + fq];
        #pragma unroll
        for (int i = 0; i < 4; ++i)
            #pragma unroll
            for (int j = 0; j < 2; ++j)
                acc[i][j] = __builtin_amdgcn_mfma_f32_16x16x32_bf16(
                    af[i], bf[j], acc[i][j], 0, 0, 0);
    }

    const int c  = lane & 15;
    const int g4 = (lane >> 4) * 4;
    #pragma unroll
    for (int i = 0; i < 4; ++i)
        #pragma unroll
        for (int j = 0; j < 2; ++j) {
            unsigned short* mp = M2b + ((size_t)(b * NDIM) + dp0 + wm + i * 16 + g4) * NDIM
                               + h * NDH + wn + j * 16 + c;
            #pragma unroll
            for (int r = 0; r < 4; ++r)
                mp[(size_t)r * NDIM] = f2bf(acc[i][j][r]);
        }
}

// ---------------------------------------------------------------------------
extern "C" void kernel_launch(void* const* d_in, const int* in_sizes, int n_in,
                              void* d_out, int out_size, void* d_ws, size_t ws_size,
                              hipStream_t stream)
{
    const float* x    = (const float*)d_in[0];
    const float* pos  = (const float*)d_in[1];
    const float* Wqkv = (const float*)d_in[2];
    const float* gk   = (const float*)d_in[3];
    const float* bk   = (const float*)d_in[4];
    const float* gv   = (const float*)d_in[5];
    const float* bv   = (const float*)d_in[6];
    const float* Wout = (const float*)d_in[7];
    const float* bout = (const float*)d_in[8];
    float* out = (float*)d_out;

    // ws: dots f32(1M) | M2b(4M) | qb(32M) | kT(32M) | vT(32M) | xb(32M)
    //     | Wqkvb(1.5M) | Woutb(.5M)
    float* dots = (float*)d_ws;
    unsigned short* M2b     = (unsigned short*)(dots + (size_t)NB * NH * 64 * 64);
    unsigned short* qb      = M2b + (size_t)NB * NDIM * NDIM;
    unsigned short* kT      = qb + (size_t)NROWS * NDIM;
    unsigned short* vT      = kT + (size_t)NB * NH * NDH * NN;
    unsigned short* xb      = vT + (size_t)NB * NH * NDH * NN;
    unsigned short* Wqkvb   = xb + (size_t)NROWS * NDIM;
    unsigned short* Woutb   = Wqkvb + (size_t)QKVC * NDIM;

    // 1) all fp32->bf16 converts + dots zeroing, one launch
    cvt_all<<<dim3(8768), dim3(256), 0, stream>>>(x, Wqkv, Wout, xb, Wqkvb, Woutb, dots);
    // 2a) k/v -> kT/vT (transposed), LN + RoPE(k) fused (BK=64 core)
    gemm_kv_fused<<<dim3(8, NROWS / 256), dim3(512), 0, stream>>>(
        xb, Wqkvb + (size_t)512 * NDIM, pos, gk, bk, gv, bv, kT, vT);
    // 2b) q -> qb row-major, RoPE fused (BK=64 core)
    gemm_q_fused<<<dim3(4, NROWS / 256), dim3(512), 0, stream>>>(
        xb, Wqkvb, pos, qb);
    // 3) dots = k^T v per (b,h)  -- MFMA, fp32 atomics
    dots_mfma<<<dim3(NN / 512, NH, NB), dim3(256), 0, stream>>>(kT, vT, dots);
    // 4) M2b[b] = ((dots[b]/N) @ blockdiag) x Wout^T  (cvt fused in)
    dotsw_mfma<<<dim3(NDIM / 128, NH, NB), dim3(256), 0, stream>>>(Woutb, dots, M2b);
    // 5) out = q @ M2b[b]^T + bout  (BK=64 core, fp32 out)
    gemm_out_mfma<<<dim3(NDIM / 128, NROWS / 256), dim3(512), 0, stream>>>(
        qb, M2b, bout, out);
}